// Round 1
// baseline (4069.014 us; speedup 1.0000x reference)
//
#include <hip/hip_runtime.h>

// ============================================================================
// PolyAlexNet forward, fp32 baseline.
//   conv layers: implicit GEMM (M=OC, N=OH*OW per image, K=C*R*S),
//   64x64 block tile, 256 thr, 4x4 regs/thread, KC=16 LDS chunks.
//   Poly epilogue (y + bias + 1)^2 fused into conv.
//   FC layers: skinny GEMM (M=64) with K-split + atomicAdd.
// ============================================================================

// ---------------------------------------------------------------- conv+poly
template<int C,int H,int W,int OC,int R,int S,int PAD,int STRIDE,int OH,int OW>
__global__ __launch_bounds__(256)
void conv_poly(const float* __restrict__ in, const float* __restrict__ wt,
               const float* __restrict__ bias, float* __restrict__ out)
{
    constexpr int K  = C * R * S;
    constexpr int NP = OH * OW;

    __shared__ float As[16][68];   // [k][oc]  (+4 pad keeps b128 alignment, spreads banks)
    __shared__ float Bs[16][68];   // [k][pix]

    const int t   = threadIdx.x;
    const int p0  = blockIdx.x * 64;
    const int oc0 = blockIdx.y * 64;
    const int b   = blockIdx.z;

    const int tx = t & 15;
    const int ty = t >> 4;

    float acc[4][4];
    #pragma unroll
    for (int i = 0; i < 4; ++i)
        #pragma unroll
        for (int j = 0; j < 4; ++j) acc[i][j] = 0.f;

    // staging index split
    const int a_oc = t >> 2;         // 0..63
    const int a_k  = (t & 3) * 4;    // 0,4,8,12
    const int b_p  = t & 63;         // 0..63
    const int b_k  = (t >> 6) * 4;   // 0,4,8,12

    const int pix = p0 + b_p;
    const int oy  = pix / OW;              // compile-time OW -> magic mul
    const int ox  = pix - oy * OW;
    const float* __restrict__ inb = in + (size_t)b * C * H * W;

    const bool a_oc_ok = (oc0 + a_oc) < OC;
    const bool b_p_ok  = pix < NP;

    for (int kc = 0; kc < K; kc += 16) {
        // ---- stage A: weights transposed, As[k][oc]; wt is [OC][K] row-major
        #pragma unroll
        for (int i = 0; i < 4; ++i) {
            const int k = kc + a_k + i;
            float v = 0.f;
            if (a_oc_ok && k < K) v = wt[(size_t)(oc0 + a_oc) * K + k];
            As[a_k + i][a_oc] = v;
        }
        // ---- stage B: im2col gather, Bs[k][pix]
        #pragma unroll
        for (int i = 0; i < 4; ++i) {
            const int k = kc + b_k + i;
            float v = 0.f;
            if (b_p_ok && k < K) {
                const int c  = k / (R * S);          // compile-time divisor
                const int rs = k - c * (R * S);
                const int r  = rs / S;
                const int s  = rs - r * S;
                const int iy = oy * STRIDE + r - PAD;
                const int ix = ox * STRIDE + s - PAD;
                if (iy >= 0 && iy < H && ix >= 0 && ix < W)
                    v = inb[(c * H + iy) * W + ix];
            }
            Bs[b_k + i][b_p] = v;
        }
        __syncthreads();

        #pragma unroll
        for (int k = 0; k < 16; ++k) {
            const float4 av = *(const float4*)(&As[k][ty * 4]);
            const float4 bv = *(const float4*)(&Bs[k][tx * 4]);
            const float a0[4] = {av.x, av.y, av.z, av.w};
            const float b0[4] = {bv.x, bv.y, bv.z, bv.w};
            #pragma unroll
            for (int i = 0; i < 4; ++i)
                #pragma unroll
                for (int j = 0; j < 4; ++j)
                    acc[i][j] += a0[i] * b0[j];
        }
        __syncthreads();
    }

    // ---- poly epilogue: (acc + bias + 1)^2
    #pragma unroll
    for (int i = 0; i < 4; ++i) {
        const int oc = oc0 + ty * 4 + i;
        if (oc >= OC) continue;
        const float bi = bias[oc] + 1.0f;
        float* __restrict__ orow = out + ((size_t)(b * OC + oc)) * NP;
        #pragma unroll
        for (int j = 0; j < 4; ++j) {
            const int p = p0 + tx * 4 + j;
            if (p < NP) {
                const float y = acc[i][j] + bi;
                orow[p] = y * y;
            }
        }
    }
}

// ---------------------------------------------------------------- avgpool 3x3 s2
__global__ __launch_bounds__(256)
void avgpool3s2_k(const float* __restrict__ in, float* __restrict__ out,
                  int BC, int H, int W, int OH, int OW)
{
    const int idx = blockIdx.x * 256 + threadIdx.x;
    const int total = BC * OH * OW;
    if (idx >= total) return;
    const int ox  = idx % OW;
    const int tmp = idx / OW;
    const int oy  = tmp % OH;
    const int bc  = tmp / OH;
    const float* __restrict__ p = in + ((size_t)bc * H + oy * 2) * W + ox * 2;
    float s = 0.f;
    #pragma unroll
    for (int r = 0; r < 3; ++r)
        #pragma unroll
        for (int c = 0; c < 3; ++c) s += p[r * W + c];
    out[idx] = s * (1.0f / 9.0f);
}

// ---------------------------------------------------------------- bias init
__global__ __launch_bounds__(256)
void bias_init_k(float* __restrict__ out, const float* __restrict__ bias,
                 int total, int N)
{
    const int idx = blockIdx.x * 256 + threadIdx.x;
    if (idx >= total) return;
    out[idx] = bias[idx % N];
}

// ---------------------------------------------------------------- FC GEMM (M=64)
// out[64][N] += X[64][K-slice] @ Wm[K-slice][N]   via atomicAdd (K-split)
__global__ __launch_bounds__(256)
void fc_gemm(const float* __restrict__ X, const float* __restrict__ Wm,
             float* __restrict__ out, int N, int K, int kchunk)
{
    __shared__ float Xs[16][68];   // [k][m]
    __shared__ float Ws[16][68];   // [k][n]

    const int t  = threadIdx.x;
    const int n0 = blockIdx.x * 64;
    const int k0 = blockIdx.y * kchunk;
    const int k1 = min(K, k0 + kchunk);

    const int tx = t & 15;
    const int ty = t >> 4;

    float acc[4][4];
    #pragma unroll
    for (int i = 0; i < 4; ++i)
        #pragma unroll
        for (int j = 0; j < 4; ++j) acc[i][j] = 0.f;

    const int x_m = t >> 2;          // 0..63 (= batch row)
    const int x_k = (t & 3) * 4;
    const int w_n = t & 63;
    const int w_k = (t >> 6) * 4;
    const bool n_ok = (n0 + w_n) < N;

    for (int kc = k0; kc < k1; kc += 16) {
        #pragma unroll
        for (int i = 0; i < 4; ++i) {
            const int k = kc + x_k + i;
            Xs[x_k + i][x_m] = (k < k1) ? X[(size_t)x_m * K + k] : 0.f;
        }
        #pragma unroll
        for (int i = 0; i < 4; ++i) {
            const int k = kc + w_k + i;
            float v = 0.f;
            if (n_ok && k < k1) v = Wm[(size_t)k * N + n0 + w_n];
            Ws[w_k + i][w_n] = v;
        }
        __syncthreads();

        #pragma unroll
        for (int k = 0; k < 16; ++k) {
            const float4 xv = *(const float4*)(&Xs[k][ty * 4]);
            const float4 wv = *(const float4*)(&Ws[k][tx * 4]);
            const float a0[4] = {xv.x, xv.y, xv.z, xv.w};
            const float b0[4] = {wv.x, wv.y, wv.z, wv.w};
            #pragma unroll
            for (int i = 0; i < 4; ++i)
                #pragma unroll
                for (int j = 0; j < 4; ++j)
                    acc[i][j] += a0[i] * b0[j];
        }
        __syncthreads();
    }

    #pragma unroll
    for (int i = 0; i < 4; ++i) {
        const int m = ty * 4 + i;    // 0..63
        #pragma unroll
        for (int j = 0; j < 4; ++j) {
            const int n = n0 + tx * 4 + j;
            if (n < N) atomicAdd(&out[(size_t)m * N + n], acc[i][j]);
        }
    }
}

// ============================================================================
extern "C" void kernel_launch(void* const* d_in, const int* in_sizes, int n_in,
                              void* d_out, int out_size, void* d_ws, size_t ws_size,
                              hipStream_t stream)
{
    const float* x   = (const float*)d_in[0];
    const float* w1  = (const float*)d_in[1];
    const float* b1  = (const float*)d_in[2];
    const float* w2  = (const float*)d_in[3];
    const float* b2  = (const float*)d_in[4];
    const float* w3  = (const float*)d_in[5];
    const float* b3  = (const float*)d_in[6];
    const float* w4  = (const float*)d_in[7];
    const float* b4  = (const float*)d_in[8];
    const float* w5  = (const float*)d_in[9];
    const float* b5  = (const float*)d_in[10];
    const float* fw1 = (const float*)d_in[11];
    const float* fb1 = (const float*)d_in[12];
    const float* fw2 = (const float*)d_in[13];
    const float* fb2 = (const float*)d_in[14];
    const float* fw3 = (const float*)d_in[15];
    const float* fb3 = (const float*)d_in[16];
    float* out = (float*)d_out;

    char* ws = (char*)d_ws;
    float* A  = (float*)ws;                                    // needs <= 74.4 MB
    float* Bb = (float*)(ws + (size_t)76 * 1024 * 1024);       // needs <= 17.9 MB

    const int B = 64;

    // conv1: [64,3,227,227] -> [64,96,55,55], stride 4
    conv_poly<3,227,227,96,11,11,0,4,55,55>
        <<<dim3(48, 2, B), 256, 0, stream>>>(x, w1, b1, A);

    // pool1: 55 -> 27
    {
        int total = B * 96 * 27 * 27;
        avgpool3s2_k<<<(total + 255) / 256, 256, 0, stream>>>(A, Bb, B * 96, 55, 55, 27, 27);
    }

    // conv2: [64,96,27,27] -> [64,256,27,27], 5x5 pad 2
    conv_poly<96,27,27,256,5,5,2,1,27,27>
        <<<dim3(12, 4, B), 256, 0, stream>>>(Bb, w2, b2, A);

    // pool2: 27 -> 13
    {
        int total = B * 256 * 13 * 13;
        avgpool3s2_k<<<(total + 255) / 256, 256, 0, stream>>>(A, Bb, B * 256, 27, 27, 13, 13);
    }

    // conv3: [64,256,13,13] -> [64,384,13,13]
    conv_poly<256,13,13,384,3,3,1,1,13,13>
        <<<dim3(3, 6, B), 256, 0, stream>>>(Bb, w3, b3, A);

    // conv4: [64,384,13,13] -> [64,384,13,13]
    conv_poly<384,13,13,384,3,3,1,1,13,13>
        <<<dim3(3, 6, B), 256, 0, stream>>>(A, w4, b4, Bb);

    // conv5: [64,384,13,13] -> [64,256,13,13]
    conv_poly<384,13,13,256,3,3,1,1,13,13>
        <<<dim3(3, 4, B), 256, 0, stream>>>(Bb, w5, b5, A);

    // pool5: 13 -> 6   -> Bb = [64, 9216] flat
    {
        int total = B * 256 * 6 * 6;
        avgpool3s2_k<<<(total + 255) / 256, 256, 0, stream>>>(A, Bb, B * 256, 13, 13, 6, 6);
    }

    // fc1: [64,9216] @ [9216,4096] + fb1 -> A
    {
        int total = B * 4096;
        bias_init_k<<<(total + 255) / 256, 256, 0, stream>>>(A, fb1, total, 4096);
        fc_gemm<<<dim3(4096 / 64, 4), 256, 0, stream>>>(Bb, fw1, A, 4096, 9216, 2304);
    }
    // fc2: [64,4096] @ [4096,4096] + fb2 -> Bb
    {
        int total = B * 4096;
        bias_init_k<<<(total + 255) / 256, 256, 0, stream>>>(Bb, fb2, total, 4096);
        fc_gemm<<<dim3(4096 / 64, 4), 256, 0, stream>>>(A, fw2, Bb, 4096, 4096, 1024);
    }
    // fc3: [64,4096] @ [4096,1000] + fb3 -> d_out
    {
        int total = B * 1000;
        bias_init_k<<<(total + 255) / 256, 256, 0, stream>>>(out, fb3, total, 1000);
        fc_gemm<<<dim3((1000 + 63) / 64, 8), 256, 0, stream>>>(Bb, fw3, out, 1000, 4096, 512);
    }
}

// Round 2
// 1436.862 us; speedup vs baseline: 2.8319x; 2.8319x over previous
//
#include <hip/hip_runtime.h>

// ============================================================================
// PolyAlexNet forward, fp16-MFMA rewrite (round 2).
//   Activations: NHWC fp16.  Accumulation: fp32 (MFMA AGPRs).
//   conv: implicit GEMM, 128x128 tile, 4 waves, 4x4 mfma_f32_16x16x32_f16,
//         K-order (r,s,c) so im2col staging is contiguous 16B vector loads.
//   Weights pre-permuted per launch to [OC][(r*S+s)*C+c] fp16, K padded to 32.
//   Poly epilogue (acc + bias + 1)^2 fused.
//   FC layers: round-1 fp32 path (memory/VALU small), inputs fp32 in ws.
// ============================================================================

typedef _Float16 f16;
typedef _Float16 f16x8 __attribute__((ext_vector_type(8)));
typedef float    f32x4 __attribute__((ext_vector_type(4)));

#define LDST 40   // LDS row stride in f16 (80 B: 16B-aligned, ~2-way banks)
#define CDIV(a,b) (((a)+(b)-1)/(b))

// ---------------------------------------------------------------- conv+poly
// D = A*B: A = weights [OC x K], B = im2col [K x N], N = 64*OH*OW pixels.
// MFMA 16x16x32 f16 layouts (learn_hip verified):
//   A-frag: m = lane&15, k = (lane>>4)*8 + j
//   B-frag: n = lane&15, k = (lane>>4)*8 + j
//   C/D   : n = lane&15, m(row) = (lane>>4)*4 + reg
template<int C,int H,int W,int OC,int R,int S,int PAD,int STRIDE,int OH,int OW,bool SCALARB>
__global__ __launch_bounds__(256)
void conv_mfma(const f16* __restrict__ in, const f16* __restrict__ wt,
               const float* __restrict__ bias, f16* __restrict__ out)
{
    constexpr int KTOT = C * R * S;
    constexpr int KP   = (KTOT + 31) & ~31;
    constexpr int OHW  = OH * OW;
    constexpr int NTOT = 64 * OHW;

    __shared__ f16 As[128][LDST];   // [oc_local][k]
    __shared__ f16 Bs[128][LDST];   // [n_local][k]

    const int t   = threadIdx.x;
    const int n0  = blockIdx.x * 128;
    const int oc0 = blockIdx.y * 128;

    // ---- staging ids: thread stages one 16-f16 half-row of A and of B
    const int srow = t >> 1;          // 0..127
    const int skh  = (t & 1) * 16;    // 0 or 16

    // pixel decompose (once; compile-time divisors -> magic mul)
    const int  n      = n0 + srow;
    const bool nvalid = n < NTOT;
    const int  ncl    = nvalid ? n : 0;
    const int  img    = ncl / OHW;
    const int  rem    = ncl - img * OHW;
    const int  oy     = rem / OW;
    const int  ox     = rem - oy * OW;

    const int  aoc    = oc0 + srow;
    const bool avalid = aoc < OC;
    const f16* __restrict__ wrow = wt + (size_t)aoc * KP + skh;

    // conv1 scalar-path base: pad==0 there, so (iy,ix) always in range
    const size_t sb_base = ((size_t)(img * H + oy * STRIDE) * W + ox * STRIDE) * C;

    // ---- wave / lane ids
    const int wv = t >> 6;
    const int wm = (wv >> 1) * 64;    // wave m-offset within 128
    const int wn = (wv & 1) * 64;     // wave n-offset within 128
    const int l  = t & 63;
    const int il = l & 15;
    const int q  = l >> 4;

    f32x4 acc[4][4];
    #pragma unroll
    for (int i = 0; i < 4; ++i)
        #pragma unroll
        for (int j = 0; j < 4; ++j)
            acc[i][j] = (f32x4){0.f, 0.f, 0.f, 0.f};

    for (int kc = 0; kc < KP; kc += 32) {
        // ---- stage A (weights; KP zero-padded at transform time)
        {
            int4 v0 = {0,0,0,0}, v1 = {0,0,0,0};
            if (avalid) {
                const int4* p = (const int4*)(wrow + kc);
                v0 = p[0]; v1 = p[1];
            }
            *(int4*)&As[srow][skh]     = v0;
            *(int4*)&As[srow][skh + 8] = v1;
        }
        // ---- stage B (im2col)
        if (SCALARB) {
            // generic per-element path (conv1: C=3, pad 0 -> no spatial bounds)
            #pragma unroll
            for (int i = 0; i < 16; ++i) {
                const int k = kc + skh + i;
                f16 v = (f16)0.f;
                if (nvalid && k < KTOT) {
                    const int r  = k / (S * C);
                    const int sc = k - r * (S * C);
                    v = in[sb_base + (size_t)r * (W * C) + sc];
                }
                Bs[srow][skh + i] = v;
            }
        } else {
            // vector path: C % 16 == 0 -> a 16-run has fixed (r,s)
            const int k16 = kc + skh;
            const int rs  = k16 / C;
            const int c0  = k16 - rs * C;
            const int r   = rs / S;
            const int s   = rs - r * S;
            const int iy  = oy * STRIDE + r - PAD;
            const int ix  = ox * STRIDE + s - PAD;
            int4 v0 = {0,0,0,0}, v1 = {0,0,0,0};
            if (nvalid && iy >= 0 && iy < H && ix >= 0 && ix < W) {
                const int4* p = (const int4*)(in + ((size_t)(img * H + iy) * W + ix) * C + c0);
                v0 = p[0]; v1 = p[1];
            }
            *(int4*)&Bs[srow][skh]     = v0;
            *(int4*)&Bs[srow][skh + 8] = v1;
        }
        __syncthreads();

        // ---- fragments + 16 MFMAs
        f16x8 af[4], bf[4];
        #pragma unroll
        for (int mi = 0; mi < 4; ++mi)
            af[mi] = *(const f16x8*)&As[wm + mi * 16 + il][q * 8];
        #pragma unroll
        for (int ni = 0; ni < 4; ++ni)
            bf[ni] = *(const f16x8*)&Bs[wn + ni * 16 + il][q * 8];
        #pragma unroll
        for (int mi = 0; mi < 4; ++mi)
            #pragma unroll
            for (int ni = 0; ni < 4; ++ni)
                acc[mi][ni] = __builtin_amdgcn_mfma_f32_16x16x32_f16(
                    af[mi], bf[ni], acc[mi][ni], 0, 0, 0);
        __syncthreads();
    }

    // ---- poly epilogue: out[n][oc] = (acc + bias[oc] + 1)^2, NHWC fp16
    #pragma unroll
    for (int mi = 0; mi < 4; ++mi) {
        const int ocb = oc0 + wm + mi * 16 + q * 4;   // 4 consecutive oc
        if (ocb >= OC) continue;                      // OC%16==0 -> subtile-whole
        const float4 bb = *(const float4*)(bias + ocb);
        const float b4[4] = {bb.x + 1.f, bb.y + 1.f, bb.z + 1.f, bb.w + 1.f};
        #pragma unroll
        for (int ni = 0; ni < 4; ++ni) {
            const int nn = n0 + wn + ni * 16 + il;
            if (nn >= NTOT) continue;
            const f32x4 v = acc[mi][ni];
            union { f16 h[4]; uint2 u; } cv;
            const float vv[4] = {v.x, v.y, v.z, v.w};
            #pragma unroll
            for (int rr = 0; rr < 4; ++rr) {
                const float y = vv[rr] + b4[rr];
                cv.h[rr] = (f16)(y * y);
            }
            *(uint2*)(out + (size_t)nn * OC + ocb) = cv.u;
        }
    }
}

// ---------------------------------------------------------------- NHWC avgpool
__global__ __launch_bounds__(256)
void avgpool_nhwc(const f16* __restrict__ in, f16* __restrict__ out,
                  int C, int H, int W, int OH, int OW, int total)
{
    const int idx = blockIdx.x * 256 + threadIdx.x;
    if (idx >= total) return;
    const int c   = idx % C;
    int rest      = idx / C;
    const int ox  = rest % OW; rest /= OW;
    const int oy  = rest % OH;
    const int b   = rest / OH;
    const f16* __restrict__ p = in + ((size_t)(b * H + oy * 2) * W + ox * 2) * C + c;
    float s = 0.f;
    #pragma unroll
    for (int r = 0; r < 3; ++r)
        #pragma unroll
        for (int cc = 0; cc < 3; ++cc)
            s += (float)p[(r * W + cc) * C];
    out[idx] = (f16)(s * (1.f / 9.f));
}

// pool5: NHWC fp16 [64][13][13][256] -> fp32 [64][9216] in NCHW-flat order
__global__ __launch_bounds__(256)
void pool5_ncflat(const f16* __restrict__ in, float* __restrict__ out)
{
    const int idx = blockIdx.x * 256 + threadIdx.x;
    if (idx >= 64 * 6 * 6 * 256) return;
    const int c  = idx & 255;
    int rest     = idx >> 8;
    const int ox = rest % 6; rest /= 6;
    const int oy = rest % 6;
    const int b  = rest / 6;
    const f16* __restrict__ p = in + ((size_t)(b * 13 + oy * 2) * 13 + ox * 2) * 256 + c;
    float s = 0.f;
    #pragma unroll
    for (int r = 0; r < 3; ++r)
        #pragma unroll
        for (int cc = 0; cc < 3; ++cc)
            s += (float)p[(r * 13 + cc) * 256];
    out[(size_t)b * 9216 + c * 36 + oy * 6 + ox] = s * (1.f / 9.f);
}

// ---------------------------------------------------------------- transforms
// x NCHW fp32 -> NHWC fp16
__global__ __launch_bounds__(256)
void x_to_nhwc(const float* __restrict__ x, f16* __restrict__ o)
{
    const int idx = blockIdx.x * 256 + threadIdx.x;
    if (idx >= 64 * 227 * 227 * 3) return;
    const int c = idx % 3;
    int rest    = idx / 3;
    const int w = rest % 227; rest /= 227;
    const int h = rest % 227;
    const int b = rest / 227;
    o[idx] = (f16)x[(((size_t)b * 3 + c) * 227 + h) * 227 + w];
}

// weights OIHW fp32 -> [OC][(r*S+s)*C + c] fp16, K zero-padded to KP
__global__ __launch_bounds__(256)
void wt_tf(const float* __restrict__ w, f16* __restrict__ o,
           int OC, int Cc, int R, int S, int KP)
{
    const int idx = blockIdx.x * 256 + threadIdx.x;
    if (idx >= OC * KP) return;
    const int k  = idx % KP;
    const int oc = idx / KP;
    f16 v = (f16)0.f;
    if (k < Cc * R * S) {
        const int rs = k / Cc;
        const int c  = k - rs * Cc;
        const int r  = rs / S;
        const int s  = rs - r * S;
        v = (f16)w[(((size_t)oc * Cc + c) * R + r) * S + s];
    }
    o[idx] = v;
}

// ---------------------------------------------------------------- FC (fp32, round 1)
__global__ __launch_bounds__(256)
void bias_init_k(float* __restrict__ out, const float* __restrict__ bias,
                 int total, int N)
{
    const int idx = blockIdx.x * 256 + threadIdx.x;
    if (idx >= total) return;
    out[idx] = bias[idx % N];
}

__global__ __launch_bounds__(256)
void fc_gemm(const float* __restrict__ X, const float* __restrict__ Wm,
             float* __restrict__ out, int N, int K, int kchunk)
{
    __shared__ float Xs[16][68];
    __shared__ float Ws[16][68];

    const int t  = threadIdx.x;
    const int n0 = blockIdx.x * 64;
    const int k0 = blockIdx.y * kchunk;
    const int k1 = min(K, k0 + kchunk);

    const int tx = t & 15;
    const int ty = t >> 4;

    float acc[4][4];
    #pragma unroll
    for (int i = 0; i < 4; ++i)
        #pragma unroll
        for (int j = 0; j < 4; ++j) acc[i][j] = 0.f;

    const int x_m = t >> 2;
    const int x_k = (t & 3) * 4;
    const int w_n = t & 63;
    const int w_k = (t >> 6) * 4;
    const bool n_ok = (n0 + w_n) < N;

    for (int kc = k0; kc < k1; kc += 16) {
        #pragma unroll
        for (int i = 0; i < 4; ++i) {
            const int k = kc + x_k + i;
            Xs[x_k + i][x_m] = (k < k1) ? X[(size_t)x_m * K + k] : 0.f;
        }
        #pragma unroll
        for (int i = 0; i < 4; ++i) {
            const int k = kc + w_k + i;
            float v = 0.f;
            if (n_ok && k < k1) v = Wm[(size_t)k * N + n0 + w_n];
            Ws[w_k + i][w_n] = v;
        }
        __syncthreads();

        #pragma unroll
        for (int k = 0; k < 16; ++k) {
            const float4 xv = *(const float4*)(&Xs[k][ty * 4]);
            const float4 wv = *(const float4*)(&Ws[k][tx * 4]);
            const float a0[4] = {xv.x, xv.y, xv.z, xv.w};
            const float b0[4] = {wv.x, wv.y, wv.z, wv.w};
            #pragma unroll
            for (int i = 0; i < 4; ++i)
                #pragma unroll
                for (int j = 0; j < 4; ++j)
                    acc[i][j] += a0[i] * b0[j];
        }
        __syncthreads();
    }

    #pragma unroll
    for (int i = 0; i < 4; ++i) {
        const int m = ty * 4 + i;
        #pragma unroll
        for (int j = 0; j < 4; ++j) {
            const int nn = n0 + tx * 4 + j;
            if (nn < N) atomicAdd(&out[(size_t)m * N + nn], acc[i][j]);
        }
    }
}

// ============================================================================
extern "C" void kernel_launch(void* const* d_in, const int* in_sizes, int n_in,
                              void* d_out, int out_size, void* d_ws, size_t ws_size,
                              hipStream_t stream)
{
    const float* x   = (const float*)d_in[0];
    const float* w1  = (const float*)d_in[1];
    const float* b1  = (const float*)d_in[2];
    const float* w2  = (const float*)d_in[3];
    const float* b2  = (const float*)d_in[4];
    const float* w3  = (const float*)d_in[5];
    const float* b3  = (const float*)d_in[6];
    const float* w4  = (const float*)d_in[7];
    const float* b4  = (const float*)d_in[8];
    const float* w5  = (const float*)d_in[9];
    const float* b5  = (const float*)d_in[10];
    const float* fw1 = (const float*)d_in[11];
    const float* fb1 = (const float*)d_in[12];
    const float* fw2 = (const float*)d_in[13];
    const float* fb2 = (const float*)d_in[14];
    const float* fw3 = (const float*)d_in[15];
    const float* fb3 = (const float*)d_in[16];
    float* out = (float*)d_out;

    char* ws = (char*)d_ws;
    const size_t MiB = 1024 * 1024;

    // region 0 .. 20 MiB: X0 (19.8 MB, dead after conv1) then F0/F1/F2 (fp32 FC)
    f16*   X0 = (f16*)(ws);
    float* F0 = (float*)(ws);                 // 64*9216*4 = 2.36 MB
    float* F1 = (float*)(ws + 3 * MiB);       // 64*4096*4 = 1 MB
    float* F2 = (float*)(ws + 5 * MiB);       // 1 MB
    f16*   A  = (f16*)(ws + 20 * MiB);        // <= 37.2 MB (conv1 out)
    f16*   Bp = (f16*)(ws + 58 * MiB);        // <= 23.9 MB (conv2 out)
    f16*   Wt1 = (f16*)(ws + 84 * MiB);       // packed fp16 weights (~7.5 MB)
    f16*   Wt2 = Wt1 + (size_t)96  * 384;
    f16*   Wt3 = Wt2 + (size_t)256 * 2400;
    f16*   Wt4 = Wt3 + (size_t)384 * 2304;
    f16*   Wt5 = Wt4 + (size_t)384 * 3456;

    // ---- weight transforms (tiny)
    wt_tf<<<CDIV(96  * 384 , 256), 256, 0, stream>>>(w1, Wt1, 96 , 3  , 11, 11, 384);
    wt_tf<<<CDIV(256 * 2400, 256), 256, 0, stream>>>(w2, Wt2, 256, 96 , 5 , 5 , 2400);
    wt_tf<<<CDIV(384 * 2304, 256), 256, 0, stream>>>(w3, Wt3, 384, 256, 3 , 3 , 2304);
    wt_tf<<<CDIV(384 * 3456, 256), 256, 0, stream>>>(w4, Wt4, 384, 384, 3 , 3 , 3456);
    wt_tf<<<CDIV(256 * 3456, 256), 256, 0, stream>>>(w5, Wt5, 256, 384, 3 , 3 , 3456);

    // ---- input to NHWC fp16
    x_to_nhwc<<<CDIV(64 * 227 * 227 * 3, 256), 256, 0, stream>>>(x, X0);

    // conv1: [64,227,227,3] -> [64,55,55,96]   N=193600
    conv_mfma<3,227,227,96,11,11,0,4,55,55,true>
        <<<dim3(CDIV(64 * 55 * 55, 128), 1), 256, 0, stream>>>(X0, Wt1, b1, A);

    // pool1: 55 -> 27 (C=96)
    {
        int total = 64 * 27 * 27 * 96;
        avgpool_nhwc<<<CDIV(total, 256), 256, 0, stream>>>(A, Bp, 96, 55, 55, 27, 27, total);
    }

    // conv2: [64,27,27,96] -> [64,27,27,256]   N=46656
    conv_mfma<96,27,27,256,5,5,2,1,27,27,false>
        <<<dim3(CDIV(64 * 27 * 27, 128), 2), 256, 0, stream>>>(Bp, Wt2, b2, A);

    // pool2: 27 -> 13 (C=256)
    {
        int total = 64 * 13 * 13 * 256;
        avgpool_nhwc<<<CDIV(total, 256), 256, 0, stream>>>(A, Bp, 256, 27, 27, 13, 13, total);
    }

    // conv3: [64,13,13,256] -> [64,13,13,384]  N=10816
    conv_mfma<256,13,13,384,3,3,1,1,13,13,false>
        <<<dim3(CDIV(64 * 13 * 13, 128), 3), 256, 0, stream>>>(Bp, Wt3, b3, A);

    // conv4: 384 -> 384
    conv_mfma<384,13,13,384,3,3,1,1,13,13,false>
        <<<dim3(CDIV(64 * 13 * 13, 128), 3), 256, 0, stream>>>(A, Wt4, b4, Bp);

    // conv5: 384 -> 256
    conv_mfma<384,13,13,256,3,3,1,1,13,13,false>
        <<<dim3(CDIV(64 * 13 * 13, 128), 2), 256, 0, stream>>>(Bp, Wt5, b5, A);

    // pool5: NHWC [64,13,13,256] -> NCHW-flat fp32 [64,9216]
    pool5_ncflat<<<CDIV(64 * 6 * 6 * 256, 256), 256, 0, stream>>>(A, F0);

    // ---- FC stack (fp32, K-split + atomics)
    {
        int total = 64 * 4096;
        bias_init_k<<<CDIV(total, 256), 256, 0, stream>>>(F1, fb1, total, 4096);
        fc_gemm<<<dim3(4096 / 64, 4), 256, 0, stream>>>(F0, fw1, F1, 4096, 9216, 2304);
    }
    {
        int total = 64 * 4096;
        bias_init_k<<<CDIV(total, 256), 256, 0, stream>>>(F2, fb2, total, 4096);
        fc_gemm<<<dim3(4096 / 64, 4), 256, 0, stream>>>(F1, fw2, F2, 4096, 4096, 1024);
    }
    {
        int total = 64 * 1000;
        bias_init_k<<<CDIV(total, 256), 256, 0, stream>>>(out, fb3, total, 1000);
        fc_gemm<<<dim3(CDIV(1000, 64), 8), 256, 0, stream>>>(F2, fw3, out, 1000, 4096, 512);
    }
}

// Round 3
// 1037.993 us; speedup vs baseline: 3.9201x; 1.3843x over previous
//
#include <hip/hip_runtime.h>

// ============================================================================
// PolyAlexNet forward (round 3).
//   convs: implicit-GEMM fp16 MFMA, NHWC, tile BMxBN (128x128 big / 64x64 small
//          for occupancy on the 13x13 layers), poly epilogue fused.
//   FCs:   fp16 MFMA, W streamed fp32 from HBM and converted in-register
//          (W is used once -> streaming beats pre-conversion), K-split +
//          fp32 atomicAdd. Memory-bound floor ~37 us for all three.
// ============================================================================

typedef _Float16 f16;
typedef _Float16 f16x8 __attribute__((ext_vector_type(8)));
typedef float    f32x4 __attribute__((ext_vector_type(4)));

#define LDST 40   // LDS row stride in f16 (80 B, 16B-aligned, spreads banks)
#define CDIV(a,b) (((a)+(b)-1)/(b))

// ---------------------------------------------------------------- conv+poly
// D = A*B: A = weights [OC x K], B = im2col [K x N], N = 64*OH*OW pixels.
// mfma_f32_16x16x32_f16 layouts: A/B-frag: row = lane&15, k = (lane>>4)*8+j
//                                C/D: col(n) = lane&15, row(m) = (lane>>4)*4+reg
template<int C,int H,int W,int OC,int R,int S,int PAD,int STRIDE,int OH,int OW,
         bool SCALARB,int BM,int BN>
__global__ __launch_bounds__(256)
void conv_mfma(const f16* __restrict__ in, const f16* __restrict__ wt,
               const float* __restrict__ bias, f16* __restrict__ out)
{
    constexpr int KTOT = C * R * S;
    constexpr int KP   = (KTOT + 31) & ~31;
    constexpr int OHW  = OH * OW;
    constexpr int NTOT = 64 * OHW;
    constexpr int AM   = BM / 32;      // m-subtiles per wave
    constexpr int AN   = BN / 32;      // n-subtiles per wave
    constexpr int AU   = BM / 64;      // A staging 16B-units per thread
    constexpr int BU   = BN / 64;      // B staging 16B-units per thread

    __shared__ __align__(16) f16 As[BM][LDST];   // [oc_local][k]
    __shared__ __align__(16) f16 Bs[BN][LDST];   // [n_local][k]

    const int t   = threadIdx.x;
    const int n0  = blockIdx.x * BN;
    const int oc0 = blockIdx.y * BM;

    // ---- per-unit staging metadata (unit = 8 f16 = 16 B; 4 units per row)
    int  a_row[AU], a_col[AU]; bool a_ok[AU];
    #pragma unroll
    for (int i = 0; i < AU; ++i) {
        const int u = t + i * 256;
        a_row[i] = u >> 2;
        a_col[i] = (u & 3) * 8;
        a_ok[i]  = (oc0 + a_row[i]) < OC;
    }
    int  b_row[BU], b_col[BU], b_img[BU], b_oy[BU], b_ox[BU]; bool b_ok[BU];
    #pragma unroll
    for (int i = 0; i < BU; ++i) {
        const int u = t + i * 256;
        b_row[i] = u >> 2;
        b_col[i] = (u & 3) * 8;
        const int n   = n0 + b_row[i];
        b_ok[i]       = n < NTOT;
        const int ncl = b_ok[i] ? n : 0;
        b_img[i] = ncl / OHW;
        const int rem = ncl - b_img[i] * OHW;
        b_oy[i]  = rem / OW;
        b_ox[i]  = rem - b_oy[i] * OW;
    }

    // ---- wave / lane ids
    const int wv = t >> 6;
    const int wm = (wv >> 1) * (BM / 2);
    const int wn = (wv & 1) * (BN / 2);
    const int l  = t & 63;
    const int il = l & 15;
    const int q  = l >> 4;

    f32x4 acc[AM][AN];
    #pragma unroll
    for (int i = 0; i < AM; ++i)
        #pragma unroll
        for (int j = 0; j < AN; ++j)
            acc[i][j] = (f32x4){0.f, 0.f, 0.f, 0.f};

    for (int kc = 0; kc < KP; kc += 32) {
        // ---- stage A (weights; KP zero-padded at transform time)
        #pragma unroll
        for (int i = 0; i < AU; ++i) {
            int4 v = {0, 0, 0, 0};
            if (a_ok[i])
                v = *(const int4*)(wt + (size_t)(oc0 + a_row[i]) * KP + kc + a_col[i]);
            *(int4*)&As[a_row[i]][a_col[i]] = v;
        }
        // ---- stage B (im2col)
        #pragma unroll
        for (int i = 0; i < BU; ++i) {
            if (SCALARB) {
                // conv1: C=3, pad 0 -> no spatial bounds, per-element gather
                const size_t sb = ((size_t)(b_img[i] * H + b_oy[i] * STRIDE) * W
                                   + b_ox[i] * STRIDE) * C;
                #pragma unroll
                for (int j = 0; j < 8; ++j) {
                    const int k = kc + b_col[i] + j;
                    f16 v = (f16)0.f;
                    if (b_ok[i] && k < KTOT) {
                        const int r  = k / (S * C);
                        const int sc = k - r * (S * C);
                        v = in[sb + (size_t)r * (W * C) + sc];
                    }
                    Bs[b_row[i]][b_col[i] + j] = v;
                }
            } else {
                // vector path: C % 8 == 0 -> an 8-run has fixed (r,s)
                const int k8 = kc + b_col[i];
                const int rs = k8 / C;
                const int c0 = k8 - rs * C;
                const int r  = rs / S;
                const int s  = rs - r * S;
                const int iy = b_oy[i] * STRIDE + r - PAD;
                const int ix = b_ox[i] * STRIDE + s - PAD;
                int4 v = {0, 0, 0, 0};
                if (b_ok[i] && iy >= 0 && iy < H && ix >= 0 && ix < W)
                    v = *(const int4*)(in + ((size_t)(b_img[i] * H + iy) * W + ix) * C + c0);
                *(int4*)&Bs[b_row[i]][b_col[i]] = v;
            }
        }
        __syncthreads();

        // ---- fragments + MFMAs
        f16x8 af[AM], bf[AN];
        #pragma unroll
        for (int mi = 0; mi < AM; ++mi)
            af[mi] = *(const f16x8*)&As[wm + mi * 16 + il][q * 8];
        #pragma unroll
        for (int ni = 0; ni < AN; ++ni)
            bf[ni] = *(const f16x8*)&Bs[wn + ni * 16 + il][q * 8];
        #pragma unroll
        for (int mi = 0; mi < AM; ++mi)
            #pragma unroll
            for (int ni = 0; ni < AN; ++ni)
                acc[mi][ni] = __builtin_amdgcn_mfma_f32_16x16x32_f16(
                    af[mi], bf[ni], acc[mi][ni], 0, 0, 0);
        __syncthreads();
    }

    // ---- poly epilogue: out[n][oc] = (acc + bias[oc] + 1)^2, NHWC fp16
    #pragma unroll
    for (int mi = 0; mi < AM; ++mi) {
        const int ocb = oc0 + wm + mi * 16 + q * 4;   // 4 consecutive oc
        if (ocb >= OC) continue;                      // OC%16==0 -> whole run valid
        const float4 bb = *(const float4*)(bias + ocb);
        const float b4[4] = {bb.x + 1.f, bb.y + 1.f, bb.z + 1.f, bb.w + 1.f};
        #pragma unroll
        for (int ni = 0; ni < AN; ++ni) {
            const int nn = n0 + wn + ni * 16 + il;
            if (nn >= NTOT) continue;
            const f32x4 v = acc[mi][ni];
            union { f16 h[4]; uint2 u; } cv;
            const float vv[4] = {v.x, v.y, v.z, v.w};
            #pragma unroll
            for (int rr = 0; rr < 4; ++rr) {
                const float y = vv[rr] + b4[rr];
                cv.h[rr] = (f16)(y * y);
            }
            *(uint2*)(out + (size_t)nn * OC + ocb) = cv.u;
        }
    }
}

// ---------------------------------------------------------------- FC MFMA
// out[64][N] += X[64][K-slice] @ W[K-slice][N]; X fp16 pre-packed, W fp32
// streamed from HBM and converted in-register. fp32 atomicAdd epilogue.
// Tile: 64(M) x 128(N); 4 waves, each 64x32 (4 m-sub x 2 n-sub).
__global__ __launch_bounds__(256)
void fc_mfma(const f16* __restrict__ X, const float* __restrict__ Wm,
             float* __restrict__ out, int N, int K, int kchunk)
{
    __shared__ __align__(16) f16 Xs[64][LDST];
    __shared__ __align__(16) f16 Ws[128][LDST];

    const int t  = threadIdx.x;
    const int n0 = blockIdx.x * 128;
    const int k0 = blockIdx.y * kchunk;
    const int k1 = k0 + kchunk;            // launch config guarantees <= K

    const int wv = t >> 6;
    const int wn = wv * 32;
    const int l  = t & 63;
    const int il = l & 15;
    const int q  = l >> 4;

    // staging ids
    const int xrow = t >> 2;               // 0..63
    const int xcol = (t & 3) * 8;          // 0,8,16,24
    const int wnl  = t & 127;              // n-local for W staging
    const int wkg0 = t >> 7;               // 0..1
    const bool wok = (n0 + wnl) < N;

    f32x4 acc[4][2];
    #pragma unroll
    for (int i = 0; i < 4; ++i)
        #pragma unroll
        for (int j = 0; j < 2; ++j)
            acc[i][j] = (f32x4){0.f, 0.f, 0.f, 0.f};

    for (int kc = k0; kc < k1; kc += 32) {
        // X tile: one 16B load per thread
        *(int4*)&Xs[xrow][xcol] = *(const int4*)&X[(size_t)xrow * K + kc + xcol];
        // W tile: per task, 8 coalesced dword loads (64 consecutive n per
        // instruction) -> cvt -> one ds_write_b128 into k-contiguous layout
        #pragma unroll
        for (int it = 0; it < 2; ++it) {
            const int kg = wkg0 + it * 2;          // 0..3
            const int kk = kc + kg * 8;
            f16x8 h;
            #pragma unroll
            for (int j = 0; j < 8; ++j) {
                const float v = wok ? Wm[(size_t)(kk + j) * N + n0 + wnl] : 0.f;
                h[j] = (f16)v;
            }
            *(f16x8*)&Ws[wnl][kg * 8] = h;
        }
        __syncthreads();

        f16x8 af[4], bf[2];
        #pragma unroll
        for (int mi = 0; mi < 4; ++mi)
            af[mi] = *(const f16x8*)&Xs[mi * 16 + il][q * 8];
        #pragma unroll
        for (int ni = 0; ni < 2; ++ni)
            bf[ni] = *(const f16x8*)&Ws[wn + ni * 16 + il][q * 8];
        #pragma unroll
        for (int mi = 0; mi < 4; ++mi)
            #pragma unroll
            for (int ni = 0; ni < 2; ++ni)
                acc[mi][ni] = __builtin_amdgcn_mfma_f32_16x16x32_f16(
                    af[mi], bf[ni], acc[mi][ni], 0, 0, 0);
        __syncthreads();
    }

    #pragma unroll
    for (int mi = 0; mi < 4; ++mi) {
        const int m = mi * 16 + q * 4;
        #pragma unroll
        for (int ni = 0; ni < 2; ++ni) {
            const int n = n0 + wn + ni * 16 + il;
            if (n >= N) continue;
            const f32x4 v = acc[mi][ni];
            const float vv[4] = {v.x, v.y, v.z, v.w};
            #pragma unroll
            for (int rr = 0; rr < 4; ++rr)
                atomicAdd(&out[(size_t)(m + rr) * N + n], vv[rr]);
        }
    }
}

// ---------------------------------------------------------------- NHWC avgpool
__global__ __launch_bounds__(256)
void avgpool_nhwc(const f16* __restrict__ in, f16* __restrict__ out,
                  int C, int H, int W, int OH, int OW, int total)
{
    const int idx = blockIdx.x * 256 + threadIdx.x;
    if (idx >= total) return;
    const int c   = idx % C;
    int rest      = idx / C;
    const int ox  = rest % OW; rest /= OW;
    const int oy  = rest % OH;
    const int b   = rest / OH;
    const f16* __restrict__ p = in + ((size_t)(b * H + oy * 2) * W + ox * 2) * C + c;
    float s = 0.f;
    #pragma unroll
    for (int r = 0; r < 3; ++r)
        #pragma unroll
        for (int cc = 0; cc < 3; ++cc)
            s += (float)p[(r * W + cc) * C];
    out[idx] = (f16)(s * (1.f / 9.f));
}

// pool5: NHWC fp16 [64][13][13][256] -> fp16 [64][9216] in NCHW-flat order
__global__ __launch_bounds__(256)
void pool5_ncflat(const f16* __restrict__ in, f16* __restrict__ out)
{
    const int idx = blockIdx.x * 256 + threadIdx.x;
    if (idx >= 64 * 6 * 6 * 256) return;
    const int c  = idx & 255;
    int rest     = idx >> 8;
    const int ox = rest % 6; rest /= 6;
    const int oy = rest % 6;
    const int b  = rest / 6;
    const f16* __restrict__ p = in + ((size_t)(b * 13 + oy * 2) * 13 + ox * 2) * 256 + c;
    float s = 0.f;
    #pragma unroll
    for (int r = 0; r < 3; ++r)
        #pragma unroll
        for (int cc = 0; cc < 3; ++cc)
            s += (float)p[(r * 13 + cc) * 256];
    out[(size_t)b * 9216 + c * 36 + oy * 6 + ox] = (f16)(s * (1.f / 9.f));
}

// ---------------------------------------------------------------- transforms
__global__ __launch_bounds__(256)
void x_to_nhwc(const float* __restrict__ x, f16* __restrict__ o)
{
    const int idx = blockIdx.x * 256 + threadIdx.x;
    if (idx >= 64 * 227 * 227 * 3) return;
    const int c = idx % 3;
    int rest    = idx / 3;
    const int w = rest % 227; rest /= 227;
    const int h = rest % 227;
    const int b = rest / 227;
    o[idx] = (f16)x[(((size_t)b * 3 + c) * 227 + h) * 227 + w];
}

// weights OIHW fp32 -> [OC][(r*S+s)*C + c] fp16, K zero-padded to KP
__global__ __launch_bounds__(256)
void wt_tf(const float* __restrict__ w, f16* __restrict__ o,
           int OC, int Cc, int R, int S, int KP)
{
    const int idx = blockIdx.x * 256 + threadIdx.x;
    if (idx >= OC * KP) return;
    const int k  = idx % KP;
    const int oc = idx / KP;
    f16 v = (f16)0.f;
    if (k < Cc * R * S) {
        const int rs = k / Cc;
        const int c  = k - rs * Cc;
        const int r  = rs / S;
        const int s  = rs - r * S;
        v = (f16)w[(((size_t)oc * Cc + c) * R + r) * S + s];
    }
    o[idx] = v;
}

__global__ __launch_bounds__(256)
void bias_init_k(float* __restrict__ out, const float* __restrict__ bias,
                 int total, int N)
{
    const int idx = blockIdx.x * 256 + threadIdx.x;
    if (idx >= total) return;
    out[idx] = bias[idx % N];
}

__global__ __launch_bounds__(256)
void f32_to_f16(const float* __restrict__ in, f16* __restrict__ o, int n)
{
    const int idx = blockIdx.x * 256 + threadIdx.x;
    if (idx < n) o[idx] = (f16)in[idx];
}

// ============================================================================
extern "C" void kernel_launch(void* const* d_in, const int* in_sizes, int n_in,
                              void* d_out, int out_size, void* d_ws, size_t ws_size,
                              hipStream_t stream)
{
    const float* x   = (const float*)d_in[0];
    const float* w1  = (const float*)d_in[1];
    const float* b1  = (const float*)d_in[2];
    const float* w2  = (const float*)d_in[3];
    const float* b2  = (const float*)d_in[4];
    const float* w3  = (const float*)d_in[5];
    const float* b3  = (const float*)d_in[6];
    const float* w4  = (const float*)d_in[7];
    const float* b4  = (const float*)d_in[8];
    const float* w5  = (const float*)d_in[9];
    const float* b5  = (const float*)d_in[10];
    const float* fw1 = (const float*)d_in[11];
    const float* fb1 = (const float*)d_in[12];
    const float* fw2 = (const float*)d_in[13];
    const float* fb2 = (const float*)d_in[14];
    const float* fw3 = (const float*)d_in[15];
    const float* fb3 = (const float*)d_in[16];
    float* out = (float*)d_out;

    char* ws = (char*)d_ws;
    const size_t MiB = 1024 * 1024;

    // 0..20 MiB region: X0 (19.8 MB, dead after conv1) overlaid by FC buffers
    f16*   X0  = (f16*)(ws);
    f16*   Xh1 = (f16*)(ws);                  // [64][9216] f16, 1.2 MB
    float* F1  = (float*)(ws + 2 * MiB);      // 64*4096*4 = 1 MB
    f16*   Xh2 = (f16*)(ws + 4 * MiB);        // 0.5 MB
    float* F2  = (float*)(ws + 6 * MiB);      // 1 MB
    f16*   Xh3 = (f16*)(ws + 8 * MiB);        // 0.5 MB
    f16*   A   = (f16*)(ws + 20 * MiB);       // <= 37.2 MB (conv1 out)
    f16*   Bp  = (f16*)(ws + 58 * MiB);       // <= 23.9 MB
    f16*   Wt1 = (f16*)(ws + 84 * MiB);       // packed fp16 conv weights (~7.5 MB)
    f16*   Wt2 = Wt1 + (size_t)96  * 384;
    f16*   Wt3 = Wt2 + (size_t)256 * 2400;
    f16*   Wt4 = Wt3 + (size_t)384 * 2304;
    f16*   Wt5 = Wt4 + (size_t)384 * 3456;

    // ---- weight transforms (tiny)
    wt_tf<<<CDIV(96  * 384 , 256), 256, 0, stream>>>(w1, Wt1, 96 , 3  , 11, 11, 384);
    wt_tf<<<CDIV(256 * 2400, 256), 256, 0, stream>>>(w2, Wt2, 256, 96 , 5 , 5 , 2400);
    wt_tf<<<CDIV(384 * 2304, 256), 256, 0, stream>>>(w3, Wt3, 384, 256, 3 , 3 , 2304);
    wt_tf<<<CDIV(384 * 3456, 256), 256, 0, stream>>>(w4, Wt4, 384, 384, 3 , 3 , 3456);
    wt_tf<<<CDIV(256 * 3456, 256), 256, 0, stream>>>(w5, Wt5, 256, 384, 3 , 3 , 3456);

    // ---- input to NHWC fp16
    x_to_nhwc<<<CDIV(64 * 227 * 227 * 3, 256), 256, 0, stream>>>(x, X0);

    // conv1: [64,227,227,3] -> [64,55,55,96]   N=193600, 128x128 tile
    conv_mfma<3,227,227,96,11,11,0,4,55,55,true,128,128>
        <<<dim3(CDIV(64 * 55 * 55, 128), 1), 256, 0, stream>>>(X0, Wt1, b1, A);

    // pool1: 55 -> 27 (C=96)
    {
        int total = 64 * 27 * 27 * 96;
        avgpool_nhwc<<<CDIV(total, 256), 256, 0, stream>>>(A, Bp, 96, 55, 55, 27, 27, total);
    }

    // conv2: [64,27,27,96] -> [64,27,27,256]   N=46656, 128x128 tile
    conv_mfma<96,27,27,256,5,5,2,1,27,27,false,128,128>
        <<<dim3(CDIV(64 * 27 * 27, 128), 2), 256, 0, stream>>>(Bp, Wt2, b2, A);

    // pool2: 27 -> 13 (C=256)
    {
        int total = 64 * 13 * 13 * 256;
        avgpool_nhwc<<<CDIV(total, 256), 256, 0, stream>>>(A, Bp, 256, 27, 27, 13, 13, total);
    }

    // conv3..5 on 64x64 tiles: N=10816 -> grid 169*OCblocks (4x occupancy)
    conv_mfma<256,13,13,384,3,3,1,1,13,13,false,64,64>
        <<<dim3(169, 6), 256, 0, stream>>>(Bp, Wt3, b3, A);
    conv_mfma<384,13,13,384,3,3,1,1,13,13,false,64,64>
        <<<dim3(169, 6), 256, 0, stream>>>(A, Wt4, b4, Bp);
    conv_mfma<384,13,13,256,3,3,1,1,13,13,false,64,64>
        <<<dim3(169, 4), 256, 0, stream>>>(Bp, Wt5, b5, A);

    // pool5: NHWC [64,13,13,256] -> NCHW-flat fp16 [64,9216]
    pool5_ncflat<<<CDIV(64 * 6 * 6 * 256, 256), 256, 0, stream>>>(A, Xh1);

    // ---- FC stack: fp16 MFMA, W streamed fp32, K-split + atomics
    {
        int total = 64 * 4096;
        bias_init_k<<<CDIV(total, 256), 256, 0, stream>>>(F1, fb1, total, 4096);
        fc_mfma<<<dim3(32, 16), 256, 0, stream>>>(Xh1, fw1, F1, 4096, 9216, 576);
        f32_to_f16<<<CDIV(total, 256), 256, 0, stream>>>(F1, Xh2, total);
    }
    {
        int total = 64 * 4096;
        bias_init_k<<<CDIV(total, 256), 256, 0, stream>>>(F2, fb2, total, 4096);
        fc_mfma<<<dim3(32, 16), 256, 0, stream>>>(Xh2, fw2, F2, 4096, 4096, 256);
        f32_to_f16<<<CDIV(total, 256), 256, 0, stream>>>(F2, Xh3, total);
    }
    {
        int total = 64 * 1000;
        bias_init_k<<<CDIV(total, 256), 256, 0, stream>>>(out, fb3, total, 1000);
        fc_mfma<<<dim3(8, 64), 256, 0, stream>>>(Xh3, fw3, out, 1000, 4096, 64);
    }
}

// Round 4
// 858.343 us; speedup vs baseline: 4.7405x; 1.2093x over previous
//
#include <hip/hip_runtime.h>

// ============================================================================
// PolyAlexNet forward (round 4).
//   convs: unchanged from round 3 (implicit-GEMM fp16 MFMA, NHWC).
//   FCs:   rebuilt. M=64 x N=256 tile, 4 waves x (4x4) 16x16x32_f16 frags.
//          W fp32 streamed with coalesced scalar loads -> in-reg cvt ->
//          XOR-swizzled [n][k] LDS (conflict-free b128 write + b128 frag read).
//          Register prefetch of chunk i+1 under MFMAs of chunk i.
//          Split-K -> fp32 partials (NO atomics) + reduce(+bias,+f16cvt).
// ============================================================================

typedef _Float16 f16;
typedef _Float16 f16x4_t __attribute__((ext_vector_type(4)));
typedef _Float16 f16x8 __attribute__((ext_vector_type(8)));
typedef float    f32x4 __attribute__((ext_vector_type(4)));

#define LDST 40   // conv LDS row stride in f16 (80 B)
#define CDIV(a,b) (((a)+(b)-1)/(b))

// ---------------------------------------------------------------- conv+poly
template<int C,int H,int W,int OC,int R,int S,int PAD,int STRIDE,int OH,int OW,
         bool SCALARB,int BM,int BN>
__global__ __launch_bounds__(256)
void conv_mfma(const f16* __restrict__ in, const f16* __restrict__ wt,
               const float* __restrict__ bias, f16* __restrict__ out)
{
    constexpr int KTOT = C * R * S;
    constexpr int KP   = (KTOT + 31) & ~31;
    constexpr int OHW  = OH * OW;
    constexpr int NTOT = 64 * OHW;
    constexpr int AM   = BM / 32;
    constexpr int AN   = BN / 32;
    constexpr int AU   = BM / 64;
    constexpr int BU   = BN / 64;

    __shared__ __align__(16) f16 As[BM][LDST];
    __shared__ __align__(16) f16 Bs[BN][LDST];

    const int t   = threadIdx.x;
    const int n0  = blockIdx.x * BN;
    const int oc0 = blockIdx.y * BM;

    int  a_row[AU], a_col[AU]; bool a_ok[AU];
    #pragma unroll
    for (int i = 0; i < AU; ++i) {
        const int u = t + i * 256;
        a_row[i] = u >> 2;
        a_col[i] = (u & 3) * 8;
        a_ok[i]  = (oc0 + a_row[i]) < OC;
    }
    int  b_row[BU], b_col[BU], b_img[BU], b_oy[BU], b_ox[BU]; bool b_ok[BU];
    #pragma unroll
    for (int i = 0; i < BU; ++i) {
        const int u = t + i * 256;
        b_row[i] = u >> 2;
        b_col[i] = (u & 3) * 8;
        const int n   = n0 + b_row[i];
        b_ok[i]       = n < NTOT;
        const int ncl = b_ok[i] ? n : 0;
        b_img[i] = ncl / OHW;
        const int rem = ncl - b_img[i] * OHW;
        b_oy[i]  = rem / OW;
        b_ox[i]  = rem - b_oy[i] * OW;
    }

    const int wv = t >> 6;
    const int wm = (wv >> 1) * (BM / 2);
    const int wn = (wv & 1) * (BN / 2);
    const int l  = t & 63;
    const int il = l & 15;
    const int q  = l >> 4;

    f32x4 acc[AM][AN];
    #pragma unroll
    for (int i = 0; i < AM; ++i)
        #pragma unroll
        for (int j = 0; j < AN; ++j)
            acc[i][j] = (f32x4){0.f, 0.f, 0.f, 0.f};

    for (int kc = 0; kc < KP; kc += 32) {
        #pragma unroll
        for (int i = 0; i < AU; ++i) {
            int4 v = {0, 0, 0, 0};
            if (a_ok[i])
                v = *(const int4*)(wt + (size_t)(oc0 + a_row[i]) * KP + kc + a_col[i]);
            *(int4*)&As[a_row[i]][a_col[i]] = v;
        }
        #pragma unroll
        for (int i = 0; i < BU; ++i) {
            if (SCALARB) {
                const size_t sb = ((size_t)(b_img[i] * H + b_oy[i] * STRIDE) * W
                                   + b_ox[i] * STRIDE) * C;
                #pragma unroll
                for (int j = 0; j < 8; ++j) {
                    const int k = kc + b_col[i] + j;
                    f16 v = (f16)0.f;
                    if (b_ok[i] && k < KTOT) {
                        const int r  = k / (S * C);
                        const int sc = k - r * (S * C);
                        v = in[sb + (size_t)r * (W * C) + sc];
                    }
                    Bs[b_row[i]][b_col[i] + j] = v;
                }
            } else {
                const int k8 = kc + b_col[i];
                const int rs = k8 / C;
                const int c0 = k8 - rs * C;
                const int r  = rs / S;
                const int s  = rs - r * S;
                const int iy = b_oy[i] * STRIDE + r - PAD;
                const int ix = b_ox[i] * STRIDE + s - PAD;
                int4 v = {0, 0, 0, 0};
                if (b_ok[i] && iy >= 0 && iy < H && ix >= 0 && ix < W)
                    v = *(const int4*)(in + ((size_t)(b_img[i] * H + iy) * W + ix) * C + c0);
                *(int4*)&Bs[b_row[i]][b_col[i]] = v;
            }
        }
        __syncthreads();

        f16x8 af[AM], bf[AN];
        #pragma unroll
        for (int mi = 0; mi < AM; ++mi)
            af[mi] = *(const f16x8*)&As[wm + mi * 16 + il][q * 8];
        #pragma unroll
        for (int ni = 0; ni < AN; ++ni)
            bf[ni] = *(const f16x8*)&Bs[wn + ni * 16 + il][q * 8];
        #pragma unroll
        for (int mi = 0; mi < AM; ++mi)
            #pragma unroll
            for (int ni = 0; ni < AN; ++ni)
                acc[mi][ni] = __builtin_amdgcn_mfma_f32_16x16x32_f16(
                    af[mi], bf[ni], acc[mi][ni], 0, 0, 0);
        __syncthreads();
    }

    #pragma unroll
    for (int mi = 0; mi < AM; ++mi) {
        const int ocb = oc0 + wm + mi * 16 + q * 4;
        if (ocb >= OC) continue;
        const float4 bb = *(const float4*)(bias + ocb);
        const float b4[4] = {bb.x + 1.f, bb.y + 1.f, bb.z + 1.f, bb.w + 1.f};
        #pragma unroll
        for (int ni = 0; ni < AN; ++ni) {
            const int nn = n0 + wn + ni * 16 + il;
            if (nn >= NTOT) continue;
            const f32x4 v = acc[mi][ni];
            union { f16 h[4]; uint2 u; } cv;
            const float vv[4] = {v.x, v.y, v.z, v.w};
            #pragma unroll
            for (int rr = 0; rr < 4; ++rr) {
                const float y = vv[rr] + b4[rr];
                cv.h[rr] = (f16)(y * y);
            }
            *(uint2*)(out + (size_t)nn * OC + ocb) = cv.u;
        }
    }
}

// ---------------------------------------------------------------- FC GEMM v2
// P[s][64][Npad] (fp32) = X[64][k-slab] @ W[k-slab][n-tile]
// X: f16 [64][K].  W: fp32 [K][N] streamed, cvt in-reg.
// LDS layout (both operands): element (row, k) at
//   row*32 + ((k>>3) ^ (row&3))*8 + (k&7)   [f16 units; 16-B XOR swizzle]
template<bool TAIL>
__global__ __launch_bounds__(256)
void fc_mfma2(const f16* __restrict__ X, const float* __restrict__ Wm,
              float* __restrict__ P, int N, int Npad, int K, int kchunk)
{
    __shared__ __align__(16) f16 Xs[64 * 32];    // 4 KB
    __shared__ __align__(16) f16 Ws[256 * 32];   // 16 KB

    const int t  = threadIdx.x;
    const int n0 = blockIdx.x * 256;
    const int s  = blockIdx.y;
    const int k0 = s * kchunk;
    const int nIter = kchunk / 32;

    // W staging: thread t owns n_l = t, g = 0..3 (one 16-B unit each)
    const bool wok = !TAIL || (n0 + t) < N;
    const float* __restrict__ wbase = Wm + (size_t)k0 * N + n0 + t;
    // X staging: thread t owns (m = t>>2, g = t&3)
    const int xm = t >> 2;
    const int xg = t & 3;
    const f16* __restrict__ xbase = X + (size_t)xm * K + k0 + xg * 8;
    const int xoff = xm * 32 + (xg ^ (xm & 3)) * 8;

    // wave/lane
    const int wq = t >> 6;       // wave id -> n quarter
    const int l  = t & 63;
    const int il = l & 15;
    const int q  = l >> 4;

    f32x4 acc[4][4];
    #pragma unroll
    for (int i = 0; i < 4; ++i)
        #pragma unroll
        for (int j = 0; j < 4; ++j)
            acc[i][j] = (f32x4){0.f, 0.f, 0.f, 0.f};

    float wreg[4][8];
    int4  xreg;

    auto loadChunk = [&](int it) {
        const size_t kbase = (size_t)it * 32;
        #pragma unroll
        for (int g = 0; g < 4; ++g)
            #pragma unroll
            for (int j = 0; j < 8; ++j)
                wreg[g][j] = wok ? wbase[(kbase + g * 8 + j) * N] : 0.f;
        xreg = *(const int4*)(xbase + kbase);
    };

    loadChunk(0);

    for (int it = 0; it < nIter; ++it) {
        // convert + LDS write (chunk it)
        #pragma unroll
        for (int g = 0; g < 4; ++g) {
            f16x8 h;
            #pragma unroll
            for (int j = 0; j < 8; ++j) h[j] = (f16)wreg[g][j];
            *(f16x8*)&Ws[t * 32 + (g ^ (t & 3)) * 8] = h;
        }
        *(int4*)&Xs[xoff] = xreg;
        __syncthreads();

        // prefetch chunk it+1 under the MFMAs
        if (it + 1 < nIter) loadChunk(it + 1);

        f16x8 af[4], bf[4];
        #pragma unroll
        for (int mi = 0; mi < 4; ++mi) {
            const int m = mi * 16 + il;
            af[mi] = *(const f16x8*)&Xs[m * 32 + (q ^ (m & 3)) * 8];
        }
        #pragma unroll
        for (int ni = 0; ni < 4; ++ni) {
            const int n = wq * 64 + ni * 16 + il;
            bf[ni] = *(const f16x8*)&Ws[n * 32 + (q ^ (n & 3)) * 8];
        }
        #pragma unroll
        for (int mi = 0; mi < 4; ++mi)
            #pragma unroll
            for (int ni = 0; ni < 4; ++ni)
                acc[mi][ni] = __builtin_amdgcn_mfma_f32_16x16x32_f16(
                    af[mi], bf[ni], acc[mi][ni], 0, 0, 0);
        __syncthreads();
    }

    // partial store: P[s][m][n]  (Npad-wide, no predication needed)
    float* __restrict__ pb = P + (size_t)s * 64 * Npad + n0;
    #pragma unroll
    for (int mi = 0; mi < 4; ++mi) {
        const int m = mi * 16 + q * 4;
        #pragma unroll
        for (int ni = 0; ni < 4; ++ni) {
            const int n = wq * 64 + ni * 16 + il;
            const f32x4 v = acc[mi][ni];
            const float vv[4] = {v.x, v.y, v.z, v.w};
            #pragma unroll
            for (int rr = 0; rr < 4; ++rr)
                pb[(size_t)(m + rr) * Npad + n] = vv[rr];
        }
    }
}

// reduce: out[m][n] = bias[n] + sum_s P[s][m][n];  f16 or f32 out, float4-wide
template<bool F16OUT>
__global__ __launch_bounds__(256)
void fc_reduce(const float* __restrict__ P, const float* __restrict__ bias,
               f16* __restrict__ o16, float* __restrict__ o32,
               int N, int Npad, int S)
{
    const int idx = blockIdx.x * 256 + threadIdx.x;
    const int total = 64 * (N / 4);
    if (idx >= total) return;
    const int n4 = (idx % (N / 4)) * 4;
    const int m  = idx / (N / 4);
    float4 a = *(const float4*)(bias + n4);
    const float* __restrict__ p = P + (size_t)m * Npad + n4;
    for (int s = 0; s < S; ++s) {
        const float4 v = *(const float4*)(p + (size_t)s * 64 * Npad);
        a.x += v.x; a.y += v.y; a.z += v.z; a.w += v.w;
    }
    if (F16OUT) {
        union { f16 h[4]; uint2 u; } cv;
        cv.h[0] = (f16)a.x; cv.h[1] = (f16)a.y;
        cv.h[2] = (f16)a.z; cv.h[3] = (f16)a.w;
        *(uint2*)(o16 + (size_t)m * N + n4) = cv.u;
    } else {
        *(float4*)(o32 + (size_t)m * N + n4) = a;
    }
}

// ---------------------------------------------------------------- NHWC avgpool
__global__ __launch_bounds__(256)
void avgpool_nhwc(const f16* __restrict__ in, f16* __restrict__ out,
                  int C, int H, int W, int OH, int OW, int total)
{
    const int idx = blockIdx.x * 256 + threadIdx.x;
    if (idx >= total) return;
    const int c   = idx % C;
    int rest      = idx / C;
    const int ox  = rest % OW; rest /= OW;
    const int oy  = rest % OH;
    const int b   = rest / OH;
    const f16* __restrict__ p = in + ((size_t)(b * H + oy * 2) * W + ox * 2) * C + c;
    float s = 0.f;
    #pragma unroll
    for (int r = 0; r < 3; ++r)
        #pragma unroll
        for (int cc = 0; cc < 3; ++cc)
            s += (float)p[(r * W + cc) * C];
    out[idx] = (f16)(s * (1.f / 9.f));
}

// pool5: NHWC fp16 [64][13][13][256] -> fp16 [64][9216] NCHW-flat
__global__ __launch_bounds__(256)
void pool5_ncflat(const f16* __restrict__ in, f16* __restrict__ out)
{
    const int idx = blockIdx.x * 256 + threadIdx.x;
    if (idx >= 64 * 6 * 6 * 256) return;
    const int c  = idx & 255;
    int rest     = idx >> 8;
    const int ox = rest % 6; rest /= 6;
    const int oy = rest % 6;
    const int b  = rest / 6;
    const f16* __restrict__ p = in + ((size_t)(b * 13 + oy * 2) * 13 + ox * 2) * 256 + c;
    float s = 0.f;
    #pragma unroll
    for (int r = 0; r < 3; ++r)
        #pragma unroll
        for (int cc = 0; cc < 3; ++cc)
            s += (float)p[(r * 13 + cc) * 256];
    out[(size_t)b * 9216 + c * 36 + oy * 6 + ox] = (f16)(s * (1.f / 9.f));
}

// ---------------------------------------------------------------- transforms
// coalesced-read version: thread per (b,h,w), 3 plane reads, 3 f16 stores
__global__ __launch_bounds__(256)
void x_to_nhwc(const float* __restrict__ x, f16* __restrict__ o)
{
    const int idx = blockIdx.x * 256 + threadIdx.x;
    if (idx >= 64 * 227 * 227) return;
    const int hw = idx % (227 * 227);
    const int b  = idx / (227 * 227);
    const size_t plane = 227 * 227;
    const float* __restrict__ p = x + (size_t)b * 3 * plane + hw;
    f16* __restrict__ po = o + (size_t)idx * 3;
    po[0] = (f16)p[0];
    po[1] = (f16)p[plane];
    po[2] = (f16)p[2 * plane];
}

// weights OIHW fp32 -> [OC][(r*S+s)*C + c] fp16, K zero-padded to KP
__global__ __launch_bounds__(256)
void wt_tf(const float* __restrict__ w, f16* __restrict__ o,
           int OC, int Cc, int R, int S, int KP)
{
    const int idx = blockIdx.x * 256 + threadIdx.x;
    if (idx >= OC * KP) return;
    const int k  = idx % KP;
    const int oc = idx / KP;
    f16 v = (f16)0.f;
    if (k < Cc * R * S) {
        const int rs = k / Cc;
        const int c  = k - rs * Cc;
        const int r  = rs / S;
        const int s  = rs - r * S;
        v = (f16)w[(((size_t)oc * Cc + c) * R + r) * S + s];
    }
    o[idx] = v;
}

// ============================================================================
extern "C" void kernel_launch(void* const* d_in, const int* in_sizes, int n_in,
                              void* d_out, int out_size, void* d_ws, size_t ws_size,
                              hipStream_t stream)
{
    const float* x   = (const float*)d_in[0];
    const float* w1  = (const float*)d_in[1];
    const float* b1  = (const float*)d_in[2];
    const float* w2  = (const float*)d_in[3];
    const float* b2  = (const float*)d_in[4];
    const float* w3  = (const float*)d_in[5];
    const float* b3  = (const float*)d_in[6];
    const float* w4  = (const float*)d_in[7];
    const float* b4  = (const float*)d_in[8];
    const float* w5  = (const float*)d_in[9];
    const float* b5  = (const float*)d_in[10];
    const float* fw1 = (const float*)d_in[11];
    const float* fb1 = (const float*)d_in[12];
    const float* fw2 = (const float*)d_in[13];
    const float* fb2 = (const float*)d_in[14];
    const float* fw3 = (const float*)d_in[15];
    const float* fb3 = (const float*)d_in[16];
    float* out = (float*)d_out;

    char* ws = (char*)d_ws;
    const size_t MiB = 1024 * 1024;

    // 0..20 MiB: X0 (19.8 MB, dead after conv1), overlaid later by FC buffers
    f16*   X0  = (f16*)(ws);
    f16*   Xh1 = (f16*)(ws);                  // [64][9216] f16, 1.18 MB
    f16*   Xh2 = (f16*)(ws + 2 * MiB);        // [64][4096] f16, 0.5 MB
    f16*   Xh3 = (f16*)(ws + 2 * MiB + 512 * 1024);
    float* P   = (float*)(ws + 3 * MiB);      // partials, 16 MiB max
    f16*   A   = (f16*)(ws + 20 * MiB);       // <= 37.2 MB
    f16*   Bp  = (f16*)(ws + 58 * MiB);       // <= 23.9 MB
    f16*   Wt1 = (f16*)(ws + 84 * MiB);       // packed conv weights ~7.5 MB
    f16*   Wt2 = Wt1 + (size_t)96  * 384;
    f16*   Wt3 = Wt2 + (size_t)256 * 2400;
    f16*   Wt4 = Wt3 + (size_t)384 * 2304;
    f16*   Wt5 = Wt4 + (size_t)384 * 3456;

    // ---- conv weight transforms (tiny)
    wt_tf<<<CDIV(96  * 384 , 256), 256, 0, stream>>>(w1, Wt1, 96 , 3  , 11, 11, 384);
    wt_tf<<<CDIV(256 * 2400, 256), 256, 0, stream>>>(w2, Wt2, 256, 96 , 5 , 5 , 2400);
    wt_tf<<<CDIV(384 * 2304, 256), 256, 0, stream>>>(w3, Wt3, 384, 256, 3 , 3 , 2304);
    wt_tf<<<CDIV(384 * 3456, 256), 256, 0, stream>>>(w4, Wt4, 384, 384, 3 , 3 , 3456);
    wt_tf<<<CDIV(256 * 3456, 256), 256, 0, stream>>>(w5, Wt5, 256, 384, 3 , 3 , 3456);

    // ---- input to NHWC fp16 (coalesced reads)
    x_to_nhwc<<<CDIV(64 * 227 * 227, 256), 256, 0, stream>>>(x, X0);

    // conv1: [64,227,227,3] -> [64,55,55,96]
    conv_mfma<3,227,227,96,11,11,0,4,55,55,true,128,128>
        <<<dim3(CDIV(64 * 55 * 55, 128), 1), 256, 0, stream>>>(X0, Wt1, b1, A);
    {
        int total = 64 * 27 * 27 * 96;
        avgpool_nhwc<<<CDIV(total, 256), 256, 0, stream>>>(A, Bp, 96, 55, 55, 27, 27, total);
    }
    // conv2
    conv_mfma<96,27,27,256,5,5,2,1,27,27,false,128,128>
        <<<dim3(CDIV(64 * 27 * 27, 128), 2), 256, 0, stream>>>(Bp, Wt2, b2, A);
    {
        int total = 64 * 13 * 13 * 256;
        avgpool_nhwc<<<CDIV(total, 256), 256, 0, stream>>>(A, Bp, 256, 27, 27, 13, 13, total);
    }
    // conv3..5 (64x64 tiles)
    conv_mfma<256,13,13,384,3,3,1,1,13,13,false,64,64>
        <<<dim3(169, 6), 256, 0, stream>>>(Bp, Wt3, b3, A);
    conv_mfma<384,13,13,384,3,3,1,1,13,13,false,64,64>
        <<<dim3(169, 6), 256, 0, stream>>>(A, Wt4, b4, Bp);
    conv_mfma<384,13,13,256,3,3,1,1,13,13,false,64,64>
        <<<dim3(169, 4), 256, 0, stream>>>(Bp, Wt5, b5, A);

    // pool5 -> Xh1 [64][9216] f16
    pool5_ncflat<<<CDIV(64 * 6 * 6 * 256, 256), 256, 0, stream>>>(A, Xh1);

    // ---- FC stack: split-K partials + reduce (no atomics)
    // fc1: K=9216, 16 n-blocks x 16 slabs, kchunk 576
    fc_mfma2<false><<<dim3(16, 16), 256, 0, stream>>>(Xh1, fw1, P, 4096, 4096, 9216, 576);
    fc_reduce<true><<<CDIV(64 * 4096 / 4, 256), 256, 0, stream>>>(P, fb1, Xh2, nullptr, 4096, 4096, 16);
    // fc2: K=4096, 16 x 16, kchunk 256
    fc_mfma2<false><<<dim3(16, 16), 256, 0, stream>>>(Xh2, fw2, P, 4096, 4096, 4096, 256);
    fc_reduce<true><<<CDIV(64 * 4096 / 4, 256), 256, 0, stream>>>(P, fb2, Xh3, nullptr, 4096, 4096, 16);
    // fc3: N=1000 (Npad 1024), 4 n-blocks x 64 slabs, kchunk 64
    fc_mfma2<true><<<dim3(4, 64), 256, 0, stream>>>(Xh3, fw3, P, 1000, 1024, 4096, 64);
    fc_reduce<false><<<CDIV(64 * 1000 / 4, 256), 256, 0, stream>>>(P, fb3, nullptr, out, 1000, 1024, 64);
}

// Round 5
// 713.269 us; speedup vs baseline: 5.7047x; 1.2034x over previous
//
#include <hip/hip_runtime.h>

// ============================================================================
// PolyAlexNet forward (round 5).
//   convs: implicit-GEMM fp16 MFMA, NHWC.
//     - XOR-swizzled per-chunk LDS ([row][32] f16, 16B unit g at g^(row&3)):
//       conflict-free b128 staging writes AND frag reads (round-4 counter
//       showed 1.4e7 conflict cycles ~19% of conv2 with the 80B-stride layout).
//     - register prefetch: chunk k+1 global loads issued under chunk k MFMAs.
//     - conv3..5: BM=128 x BN=64 (8 MFMA : 6 ds_read per wave, ~35% ceiling)
//       instead of 64x64 (4:4, ~22% ceiling).
//   FCs: round-4 structure (split-K partials + reduce, no atomics).
// ============================================================================

typedef _Float16 f16;
typedef _Float16 f16x8 __attribute__((ext_vector_type(8)));
typedef float    f32x4 __attribute__((ext_vector_type(4)));

#define CDIV(a,b) (((a)+(b)-1)/(b))

// ---------------------------------------------------------------- conv+poly
// D = A*B: A = weights [OC x K], B = im2col [K x N], N = 64*OH*OW pixels.
// mfma_f32_16x16x32_f16: A/B-frag row = lane&15, k = (lane>>4)*8+j
//                        C/D col(n) = lane&15, row(m) = (lane>>4)*4+reg
// LDS: element (row, k in chunk) at row*32 + ((k>>3)^(row&3))*8 + (k&7)
template<int C,int H,int W,int OC,int R,int S,int PAD,int STRIDE,int OH,int OW,
         bool SCALARB,int BM,int BN>
__global__ __launch_bounds__(256)
void conv_mfma(const f16* __restrict__ in, const f16* __restrict__ wt,
               const float* __restrict__ bias, f16* __restrict__ out)
{
    constexpr int KTOT = C * R * S;
    constexpr int KP   = (KTOT + 31) & ~31;
    constexpr int OHW  = OH * OW;
    constexpr int NTOT = 64 * OHW;
    constexpr int AM   = BM / 32;          // m-subtiles per wave (wave = BM/2 x BN/2)
    constexpr int AN   = BN / 32;
    constexpr int AU   = BM * 4 / 256;     // 16B staging units per thread (A)
    constexpr int BU   = BN * 4 / 256;     // 16B staging units per thread (B)

    __shared__ __align__(16) f16 As[BM * 32];
    __shared__ __align__(16) f16 Bs[BN * 32];

    const int t   = threadIdx.x;
    const int n0  = blockIdx.x * BN;
    const int oc0 = blockIdx.y * BM;

    // ---- A staging metadata
    int a_row[AU], a_g[AU], a_lds[AU]; bool a_ok[AU];
    #pragma unroll
    for (int i = 0; i < AU; ++i) {
        const int u = t + i * 256;
        a_row[i] = u >> 2;
        a_g[i]   = u & 3;
        a_lds[i] = a_row[i] * 32 + ((a_g[i] ^ (a_row[i] & 3)) * 8);
        a_ok[i]  = (oc0 + a_row[i]) < OC;
    }
    // ---- B staging metadata (pixel decompose once)
    int b_row[BU], b_g[BU], b_lds[BU], b_img[BU], b_oy[BU], b_ox[BU]; bool b_ok[BU];
    #pragma unroll
    for (int i = 0; i < BU; ++i) {
        const int u = t + i * 256;
        b_row[i] = u >> 2;
        b_g[i]   = u & 3;
        b_lds[i] = b_row[i] * 32 + ((b_g[i] ^ (b_row[i] & 3)) * 8);
        const int n   = n0 + b_row[i];
        b_ok[i]       = n < NTOT;
        const int ncl = b_ok[i] ? n : 0;
        b_img[i] = ncl / OHW;
        const int rem = ncl - b_img[i] * OHW;
        b_oy[i]  = rem / OW;
        b_ox[i]  = rem - b_oy[i] * OW;
    }

    // ---- wave / lane ids
    const int wv = t >> 6;
    const int wm = (wv >> 1) * (BM / 2);
    const int wn = (wv & 1) * (BN / 2);
    const int l  = t & 63;
    const int il = l & 15;
    const int q  = l >> 4;

    f32x4 acc[AM][AN];
    #pragma unroll
    for (int i = 0; i < AM; ++i)
        #pragma unroll
        for (int j = 0; j < AN; ++j)
            acc[i][j] = (f32x4){0.f, 0.f, 0.f, 0.f};

    // ---- prefetch registers
    int4 aReg[AU], bReg[BU];

    auto loadA = [&](int kc) {
        #pragma unroll
        for (int i = 0; i < AU; ++i) {
            int4 v = {0, 0, 0, 0};
            if (a_ok[i])
                v = *(const int4*)(wt + (size_t)(oc0 + a_row[i]) * KP + kc + a_g[i] * 8);
            aReg[i] = v;
        }
    };
    auto loadB = [&](int kc) {
        #pragma unroll
        for (int i = 0; i < BU; ++i) {
            if (SCALARB) {
                // conv1: C=3, pad 0 -> no spatial bounds, per-element gather
                const size_t sb = ((size_t)(b_img[i] * H + b_oy[i] * STRIDE) * W
                                   + b_ox[i] * STRIDE) * C;
                union { f16 h[8]; int4 v; } cv;
                #pragma unroll
                for (int j = 0; j < 8; ++j) {
                    const int k = kc + b_g[i] * 8 + j;
                    f16 v = (f16)0.f;
                    if (b_ok[i] && k < KTOT) {
                        const int r  = k / (S * C);
                        const int sc = k - r * (S * C);
                        v = in[sb + (size_t)r * (W * C) + sc];
                    }
                    cv.h[j] = v;
                }
                bReg[i] = cv.v;
            } else {
                // vector path: C % 8 == 0 -> an 8-run has fixed (r,s)
                const int k8 = kc + b_g[i] * 8;
                const int rs = k8 / C;
                const int c0 = k8 - rs * C;
                const int r  = rs / S;
                const int s  = rs - r * S;
                const int iy = b_oy[i] * STRIDE + r - PAD;
                const int ix = b_ox[i] * STRIDE + s - PAD;
                int4 v = {0, 0, 0, 0};
                if (b_ok[i] && iy >= 0 && iy < H && ix >= 0 && ix < W)
                    v = *(const int4*)(in + ((size_t)(b_img[i] * H + iy) * W + ix) * C + c0);
                bReg[i] = v;
            }
        }
    };

    loadA(0); loadB(0);

    for (int kc = 0; kc < KP; kc += 32) {
        // ---- write prefetched chunk to LDS
        #pragma unroll
        for (int i = 0; i < AU; ++i) *(int4*)&As[a_lds[i]] = aReg[i];
        #pragma unroll
        for (int i = 0; i < BU; ++i) *(int4*)&Bs[b_lds[i]] = bReg[i];
        __syncthreads();

        // ---- prefetch next chunk under the MFMAs
        if (kc + 32 < KP) { loadA(kc + 32); loadB(kc + 32); }

        f16x8 af[AM], bf[AN];
        #pragma unroll
        for (int mi = 0; mi < AM; ++mi) {
            const int row = wm + mi * 16 + il;
            af[mi] = *(const f16x8*)&As[row * 32 + ((q ^ (row & 3)) * 8)];
        }
        #pragma unroll
        for (int ni = 0; ni < AN; ++ni) {
            const int row = wn + ni * 16 + il;
            bf[ni] = *(const f16x8*)&Bs[row * 32 + ((q ^ (row & 3)) * 8)];
        }
        #pragma unroll
        for (int mi = 0; mi < AM; ++mi)
            #pragma unroll
            for (int ni = 0; ni < AN; ++ni)
                acc[mi][ni] = __builtin_amdgcn_mfma_f32_16x16x32_f16(
                    af[mi], bf[ni], acc[mi][ni], 0, 0, 0);
        __syncthreads();
    }

    // ---- poly epilogue: out[n][oc] = (acc + bias[oc] + 1)^2, NHWC fp16
    #pragma unroll
    for (int mi = 0; mi < AM; ++mi) {
        const int ocb = oc0 + wm + mi * 16 + q * 4;
        if (ocb >= OC) continue;
        const float4 bb = *(const float4*)(bias + ocb);
        const float b4[4] = {bb.x + 1.f, bb.y + 1.f, bb.z + 1.f, bb.w + 1.f};
        #pragma unroll
        for (int ni = 0; ni < AN; ++ni) {
            const int nn = n0 + wn + ni * 16 + il;
            if (nn >= NTOT) continue;
            const f32x4 v = acc[mi][ni];
            union { f16 h[4]; uint2 u; } cv;
            const float vv[4] = {v.x, v.y, v.z, v.w};
            #pragma unroll
            for (int rr = 0; rr < 4; ++rr) {
                const float y = vv[rr] + b4[rr];
                cv.h[rr] = (f16)(y * y);
            }
            *(uint2*)(out + (size_t)nn * OC + ocb) = cv.u;
        }
    }
}

// ---------------------------------------------------------------- FC GEMM
// P[s][64][Npad] (fp32) = X[64][k-slab] @ W[k-slab][n-tile]
template<bool TAIL>
__global__ __launch_bounds__(256)
void fc_mfma2(const f16* __restrict__ X, const float* __restrict__ Wm,
              float* __restrict__ P, int N, int Npad, int K, int kchunk)
{
    __shared__ __align__(16) f16 Xs[64 * 32];    // 4 KB
    __shared__ __align__(16) f16 Ws[256 * 32];   // 16 KB

    const int t  = threadIdx.x;
    const int n0 = blockIdx.x * 256;
    const int s  = blockIdx.y;
    const int k0 = s * kchunk;
    const int nIter = kchunk / 32;

    const bool wok = !TAIL || (n0 + t) < N;
    const float* __restrict__ wbase = Wm + (size_t)k0 * N + n0 + t;
    const int xm = t >> 2;
    const int xg = t & 3;
    const f16* __restrict__ xbase = X + (size_t)xm * K + k0 + xg * 8;
    const int xoff = xm * 32 + (xg ^ (xm & 3)) * 8;

    const int wq = t >> 6;
    const int l  = t & 63;
    const int il = l & 15;
    const int q  = l >> 4;

    f32x4 acc[4][4];
    #pragma unroll
    for (int i = 0; i < 4; ++i)
        #pragma unroll
        for (int j = 0; j < 4; ++j)
            acc[i][j] = (f32x4){0.f, 0.f, 0.f, 0.f};

    float wreg[4][8];
    int4  xreg;

    auto loadChunk = [&](int it) {
        const size_t kbase = (size_t)it * 32;
        #pragma unroll
        for (int g = 0; g < 4; ++g)
            #pragma unroll
            for (int j = 0; j < 8; ++j)
                wreg[g][j] = wok ? wbase[(kbase + g * 8 + j) * N] : 0.f;
        xreg = *(const int4*)(xbase + kbase);
    };

    loadChunk(0);

    for (int it = 0; it < nIter; ++it) {
        #pragma unroll
        for (int g = 0; g < 4; ++g) {
            f16x8 h;
            #pragma unroll
            for (int j = 0; j < 8; ++j) h[j] = (f16)wreg[g][j];
            *(f16x8*)&Ws[t * 32 + (g ^ (t & 3)) * 8] = h;
        }
        *(int4*)&Xs[xoff] = xreg;
        __syncthreads();

        if (it + 1 < nIter) loadChunk(it + 1);

        f16x8 af[4], bf[4];
        #pragma unroll
        for (int mi = 0; mi < 4; ++mi) {
            const int m = mi * 16 + il;
            af[mi] = *(const f16x8*)&Xs[m * 32 + (q ^ (m & 3)) * 8];
        }
        #pragma unroll
        for (int ni = 0; ni < 4; ++ni) {
            const int n = wq * 64 + ni * 16 + il;
            bf[ni] = *(const f16x8*)&Ws[n * 32 + (q ^ (n & 3)) * 8];
        }
        #pragma unroll
        for (int mi = 0; mi < 4; ++mi)
            #pragma unroll
            for (int ni = 0; ni < 4; ++ni)
                acc[mi][ni] = __builtin_amdgcn_mfma_f32_16x16x32_f16(
                    af[mi], bf[ni], acc[mi][ni], 0, 0, 0);
        __syncthreads();
    }

    float* __restrict__ pb = P + (size_t)s * 64 * Npad + n0;
    #pragma unroll
    for (int mi = 0; mi < 4; ++mi) {
        const int m = mi * 16 + q * 4;
        #pragma unroll
        for (int ni = 0; ni < 4; ++ni) {
            const int n = wq * 64 + ni * 16 + il;
            const f32x4 v = acc[mi][ni];
            const float vv[4] = {v.x, v.y, v.z, v.w};
            #pragma unroll
            for (int rr = 0; rr < 4; ++rr)
                pb[(size_t)(m + rr) * Npad + n] = vv[rr];
        }
    }
}

// reduce: out[m][n] = bias[n] + sum_s P[s][m][n]
template<bool F16OUT>
__global__ __launch_bounds__(256)
void fc_reduce(const float* __restrict__ P, const float* __restrict__ bias,
               f16* __restrict__ o16, float* __restrict__ o32,
               int N, int Npad, int S)
{
    const int idx = blockIdx.x * 256 + threadIdx.x;
    const int total = 64 * (N / 4);
    if (idx >= total) return;
    const int n4 = (idx % (N / 4)) * 4;
    const int m  = idx / (N / 4);
    float4 a = *(const float4*)(bias + n4);
    const float* __restrict__ p = P + (size_t)m * Npad + n4;
    for (int s = 0; s < S; ++s) {
        const float4 v = *(const float4*)(p + (size_t)s * 64 * Npad);
        a.x += v.x; a.y += v.y; a.z += v.z; a.w += v.w;
    }
    if (F16OUT) {
        union { f16 h[4]; uint2 u; } cv;
        cv.h[0] = (f16)a.x; cv.h[1] = (f16)a.y;
        cv.h[2] = (f16)a.z; cv.h[3] = (f16)a.w;
        *(uint2*)(o16 + (size_t)m * N + n4) = cv.u;
    } else {
        *(float4*)(o32 + (size_t)m * N + n4) = a;
    }
}

// ---------------------------------------------------------------- NHWC avgpool
__global__ __launch_bounds__(256)
void avgpool_nhwc(const f16* __restrict__ in, f16* __restrict__ out,
                  int C, int H, int W, int OH, int OW, int total)
{
    const int idx = blockIdx.x * 256 + threadIdx.x;
    if (idx >= total) return;
    const int c   = idx % C;
    int rest      = idx / C;
    const int ox  = rest % OW; rest /= OW;
    const int oy  = rest % OH;
    const int b   = rest / OH;
    const f16* __restrict__ p = in + ((size_t)(b * H + oy * 2) * W + ox * 2) * C + c;
    float s = 0.f;
    #pragma unroll
    for (int r = 0; r < 3; ++r)
        #pragma unroll
        for (int cc = 0; cc < 3; ++cc)
            s += (float)p[(r * W + cc) * C];
    out[idx] = (f16)(s * (1.f / 9.f));
}

// pool5: NHWC fp16 [64][13][13][256] -> fp16 [64][9216] NCHW-flat
__global__ __launch_bounds__(256)
void pool5_ncflat(const f16* __restrict__ in, f16* __restrict__ out)
{
    const int idx = blockIdx.x * 256 + threadIdx.x;
    if (idx >= 64 * 6 * 6 * 256) return;
    const int c  = idx & 255;
    int rest     = idx >> 8;
    const int ox = rest % 6; rest /= 6;
    const int oy = rest % 6;
    const int b  = rest / 6;
    const f16* __restrict__ p = in + ((size_t)(b * 13 + oy * 2) * 13 + ox * 2) * 256 + c;
    float s = 0.f;
    #pragma unroll
    for (int r = 0; r < 3; ++r)
        #pragma unroll
        for (int cc = 0; cc < 3; ++cc)
            s += (float)p[(r * 13 + cc) * 256];
    out[(size_t)b * 9216 + c * 36 + oy * 6 + ox] = (f16)(s * (1.f / 9.f));
}

// ---------------------------------------------------------------- transforms
__global__ __launch_bounds__(256)
void x_to_nhwc(const float* __restrict__ x, f16* __restrict__ o)
{
    const int idx = blockIdx.x * 256 + threadIdx.x;
    if (idx >= 64 * 227 * 227) return;
    const int hw = idx % (227 * 227);
    const int b  = idx / (227 * 227);
    const size_t plane = 227 * 227;
    const float* __restrict__ p = x + (size_t)b * 3 * plane + hw;
    f16* __restrict__ po = o + (size_t)idx * 3;
    po[0] = (f16)p[0];
    po[1] = (f16)p[plane];
    po[2] = (f16)p[2 * plane];
}

// weights OIHW fp32 -> [OC][(r*S+s)*C + c] fp16, K zero-padded to KP
__global__ __launch_bounds__(256)
void wt_tf(const float* __restrict__ w, f16* __restrict__ o,
           int OC, int Cc, int R, int S, int KP)
{
    const int idx = blockIdx.x * 256 + threadIdx.x;
    if (idx >= OC * KP) return;
    const int k  = idx % KP;
    const int oc = idx / KP;
    f16 v = (f16)0.f;
    if (k < Cc * R * S) {
        const int rs = k / Cc;
        const int c  = k - rs * Cc;
        const int r  = rs / S;
        const int s  = rs - r * S;
        v = (f16)w[(((size_t)oc * Cc + c) * R + r) * S + s];
    }
    o[idx] = v;
}

// ============================================================================
extern "C" void kernel_launch(void* const* d_in, const int* in_sizes, int n_in,
                              void* d_out, int out_size, void* d_ws, size_t ws_size,
                              hipStream_t stream)
{
    const float* x   = (const float*)d_in[0];
    const float* w1  = (const float*)d_in[1];
    const float* b1  = (const float*)d_in[2];
    const float* w2  = (const float*)d_in[3];
    const float* b2  = (const float*)d_in[4];
    const float* w3  = (const float*)d_in[5];
    const float* b3  = (const float*)d_in[6];
    const float* w4  = (const float*)d_in[7];
    const float* b4  = (const float*)d_in[8];
    const float* w5  = (const float*)d_in[9];
    const float* b5  = (const float*)d_in[10];
    const float* fw1 = (const float*)d_in[11];
    const float* fb1 = (const float*)d_in[12];
    const float* fw2 = (const float*)d_in[13];
    const float* fb2 = (const float*)d_in[14];
    const float* fw3 = (const float*)d_in[15];
    const float* fb3 = (const float*)d_in[16];
    float* out = (float*)d_out;

    char* ws = (char*)d_ws;
    const size_t MiB = 1024 * 1024;

    f16*   X0  = (f16*)(ws);
    f16*   Xh1 = (f16*)(ws);                  // [64][9216] f16
    f16*   Xh2 = (f16*)(ws + 2 * MiB);
    f16*   Xh3 = (f16*)(ws + 2 * MiB + 512 * 1024);
    float* P   = (float*)(ws + 3 * MiB);      // partials, 16 MiB max
    f16*   A   = (f16*)(ws + 20 * MiB);       // <= 37.2 MB
    f16*   Bp  = (f16*)(ws + 58 * MiB);       // <= 23.9 MB
    f16*   Wt1 = (f16*)(ws + 84 * MiB);       // packed conv weights ~7.5 MB
    f16*   Wt2 = Wt1 + (size_t)96  * 384;
    f16*   Wt3 = Wt2 + (size_t)256 * 2400;
    f16*   Wt4 = Wt3 + (size_t)384 * 2304;
    f16*   Wt5 = Wt4 + (size_t)384 * 3456;

    // ---- conv weight transforms (tiny)
    wt_tf<<<CDIV(96  * 384 , 256), 256, 0, stream>>>(w1, Wt1, 96 , 3  , 11, 11, 384);
    wt_tf<<<CDIV(256 * 2400, 256), 256, 0, stream>>>(w2, Wt2, 256, 96 , 5 , 5 , 2400);
    wt_tf<<<CDIV(384 * 2304, 256), 256, 0, stream>>>(w3, Wt3, 384, 256, 3 , 3 , 2304);
    wt_tf<<<CDIV(384 * 3456, 256), 256, 0, stream>>>(w4, Wt4, 384, 384, 3 , 3 , 3456);
    wt_tf<<<CDIV(256 * 3456, 256), 256, 0, stream>>>(w5, Wt5, 256, 384, 3 , 3 , 3456);

    // ---- input to NHWC fp16
    x_to_nhwc<<<CDIV(64 * 227 * 227, 256), 256, 0, stream>>>(x, X0);

    // conv1: [64,227,227,3] -> [64,55,55,96]
    conv_mfma<3,227,227,96,11,11,0,4,55,55,true,128,128>
        <<<dim3(CDIV(64 * 55 * 55, 128), 1), 256, 0, stream>>>(X0, Wt1, b1, A);
    {
        int total = 64 * 27 * 27 * 96;
        avgpool_nhwc<<<CDIV(total, 256), 256, 0, stream>>>(A, Bp, 96, 55, 55, 27, 27, total);
    }
    // conv2: [64,27,27,96] -> [64,27,27,256]
    conv_mfma<96,27,27,256,5,5,2,1,27,27,false,128,128>
        <<<dim3(CDIV(64 * 27 * 27, 128), 2), 256, 0, stream>>>(Bp, Wt2, b2, A);
    {
        int total = 64 * 13 * 13 * 256;
        avgpool_nhwc<<<CDIV(total, 256), 256, 0, stream>>>(A, Bp, 256, 27, 27, 13, 13, total);
    }
    // conv3..5: BM=128 x BN=64 (N=10816 -> 169 n-blocks)
    conv_mfma<256,13,13,384,3,3,1,1,13,13,false,128,64>
        <<<dim3(169, 3), 256, 0, stream>>>(Bp, Wt3, b3, A);
    conv_mfma<384,13,13,384,3,3,1,1,13,13,false,128,64>
        <<<dim3(169, 3), 256, 0, stream>>>(A, Wt4, b4, Bp);
    conv_mfma<384,13,13,256,3,3,1,1,13,13,false,128,64>
        <<<dim3(169, 2), 256, 0, stream>>>(Bp, Wt5, b5, A);

    // pool5 -> Xh1 [64][9216] f16
    pool5_ncflat<<<CDIV(64 * 6 * 6 * 256, 256), 256, 0, stream>>>(A, Xh1);

    // ---- FC stack: split-K partials + reduce (no atomics)
    fc_mfma2<false><<<dim3(16, 16), 256, 0, stream>>>(Xh1, fw1, P, 4096, 4096, 9216, 576);
    fc_reduce<true><<<CDIV(64 * 4096 / 4, 256), 256, 0, stream>>>(P, fb1, Xh2, nullptr, 4096, 4096, 16);
    fc_mfma2<false><<<dim3(16, 16), 256, 0, stream>>>(Xh2, fw2, P, 4096, 4096, 4096, 256);
    fc_reduce<true><<<CDIV(64 * 4096 / 4, 256), 256, 0, stream>>>(P, fb2, Xh3, nullptr, 4096, 4096, 16);
    fc_mfma2<true><<<dim3(4, 64), 256, 0, stream>>>(Xh3, fw3, P, 1000, 1024, 4096, 64);
    fc_reduce<false><<<CDIV(64 * 1000 / 4, 256), 256, 0, stream>>>(P, fb3, nullptr, out, 1000, 1024, 64);
}